// Round 4
// baseline (331.782 us; speedup 1.0000x reference)
//
#include <hip/hip_runtime.h>
#include <hip/hip_bf16.h>
#include <stdint.h>

// B=8, S=1024, NX=1024, H=16, D=64
typedef __bf16 bf16x8 __attribute__((ext_vector_type(8)));
typedef float  f32x4  __attribute__((ext_vector_type(4)));
typedef float  f32x16 __attribute__((ext_vector_type(16)));

#define BARRIER() asm volatile("s_barrier" ::: "memory")
#define VMCNT(n)  asm volatile("s_waitcnt vmcnt(" #n ")" ::: "memory")
#define LGKM0()   asm volatile("s_waitcnt lgkmcnt(0)" ::: "memory")
#define SCHED0()  __builtin_amdgcn_sched_barrier(0)

__device__ __forceinline__ void gload_lds16(const void* g, void* l) {
  __builtin_amdgcn_global_load_lds(
      (const __attribute__((address_space(1))) unsigned int*)g,
      (__attribute__((address_space(3))) unsigned int*)l, 16, 0, 0);
}

// ---------------- cast fp32 -> bf16, 4 elems/thread ----------------
__global__ void k_cast(const float* __restrict__ in, __bf16* __restrict__ out, int n4) {
  int i = blockIdx.x * blockDim.x + threadIdx.x;
  if (i >= n4) return;
  float4 v = reinterpret_cast<const float4*>(in)[i];
  union { __bf16 h[4]; uint64_t u; } c;
  c.h[0] = (__bf16)v.x; c.h[1] = (__bf16)v.y; c.h[2] = (__bf16)v.z; c.h[3] = (__bf16)v.w;
  *reinterpret_cast<uint64_t*>(out + 4l * i) = c.u;
}

// ------------- transpose fp32 [R][C] -> bf16 [C][R] ----------------
__global__ void k_transpose_cast(const float* __restrict__ in, __bf16* __restrict__ out,
                                 int R, int C) {
  __shared__ float t[32][33];
  const int tx = threadIdx.x & 31, ty = threadIdx.x >> 5;  // 32 x 8
  const int c0 = blockIdx.x * 32, r0 = blockIdx.y * 32;
#pragma unroll
  for (int rr = 0; rr < 4; ++rr)
    t[ty * 4 + rr][tx] = in[(long)(r0 + ty * 4 + rr) * C + c0 + tx];
  __syncthreads();
#pragma unroll
  for (int rr = 0; rr < 4; ++rr)
    out[(long)(c0 + ty * 4 + rr) * R + r0 + tx] = (__bf16)t[tx][ty * 4 + rr];
}

// ============ pipelined GEMM: C = A[M,K] * Bt[N,K]^T + bias ============
// Tile 256x128, BK=64, 8 waves (2m x 4n), per-wave C = 128x32 (acc[8][2]).
// LDS: 3 rotating buffers x {A 256x64 (32K), B 128x64 (16K)} = 144 KB.
// Prefetch depth = 2 K-tiles; stage A[t+2] in ph0, B[t+2]+vmcnt(6) in ph1.
// Steady state 6-12 loads in flight; vmcnt(0) only on the last 2 tiles.
// Swizzle (T2): byte-col ^= ((row&7)<<4) on gload source AND ds_read.
// MODE 0: scatter -> q[B,H,S,D] (pre-scaled 1/8), k[B,H,S,D], v^T[B,H,D,S]
// MODE 1: fp32 -> fo[M,N]
template <int MODE>
__launch_bounds__(512, 2)
__global__ void k_gemm_p(const __bf16* __restrict__ A, const __bf16* __restrict__ Bt,
                         const float* __restrict__ bias, int M, int N, int K, int NB,
                         __bf16* __restrict__ qo, __bf16* __restrict__ ko,
                         __bf16* __restrict__ vo, float* __restrict__ fo) {
  __shared__ __bf16 lds[3][24576];  // [buf][A: 0..16384 | B: 16384..24576]
  const int tid = threadIdx.x;
  const int l = tid & 63;
  const int w = tid >> 6;
  const int lm = l & 15, lq = l >> 4;
  const int wm = w >> 2, wn = w & 3;
  const int nwg = gridDim.x;
  const int wg = (blockIdx.x & 7) * (nwg >> 3) + (blockIdx.x >> 3);  // XCD swizzle (nwg%8==0)
  const int bm = wg / NB, bn = wg % NB;
  const int nt = K >> 6;

  // ---- staging addresses: thread covers row (tid>>3)+li*64, 16B at swizzled col ----
  const int rA = tid >> 3;
  const int scol = (((tid & 7) * 16) ^ ((rA & 7) << 4)) >> 1;  // element col (swizzled)
  long a_off[4], b_off[2];
#pragma unroll
  for (int li = 0; li < 4; ++li) a_off[li] = (long)(bm * 256 + li * 64 + rA) * K + scol;
#pragma unroll
  for (int li = 0; li < 2; ++li) b_off[li] = (long)(bn * 128 + li * 64 + rA) * K + scol;

#define STAGE_A(buf, t) { \
    gload_lds16(A + a_off[0] + (long)(t) * 64, &lds[buf][tid * 8]); \
    gload_lds16(A + a_off[1] + (long)(t) * 64, &lds[buf][4096 + tid * 8]); \
    gload_lds16(A + a_off[2] + (long)(t) * 64, &lds[buf][8192 + tid * 8]); \
    gload_lds16(A + a_off[3] + (long)(t) * 64, &lds[buf][12288 + tid * 8]); }
#define STAGE_B(buf, t) { \
    gload_lds16(Bt + b_off[0] + (long)(t) * 64, &lds[buf][16384 + tid * 8]); \
    gload_lds16(Bt + b_off[1] + (long)(t) * 64, &lds[buf][20480 + tid * 8]); }

  // ---- fragment read offsets ----
  const int aswz = (lm & 7) << 4;
  const int cofs0 = ((0 * 64 + lq * 16) ^ aswz) >> 1;   // ks=0 element col
  const int cofs1 = ((1 * 64 + lq * 16) ^ aswz) >> 1;   // ks=1
  const int arow = wm * 128 + lm;                        // + mi*16
  const int brow = wn * 32 + lm;                         // + nj*16

  f32x4 acc[8][2] = {};

  // ---- prologue: stage tiles 0,1 (12 loads); retire tile 0's 6 ----
  STAGE_A(0, 0); STAGE_B(0, 0);
  STAGE_A(1, 1); STAGE_B(1, 1);
  VMCNT(6); BARRIER();

  for (int t = 0; t < nt; ++t) {
    const int cb = t % 3;
    const __bf16* Lb = lds[cb];
    // ======== phase 0: read B(4) + A mi0-3(8); stage A[t+2]; MFMA mi0-3 ========
    bf16x8 bf[2][2], af[4][2];
#pragma unroll
    for (int nj = 0; nj < 2; ++nj) {
      bf[nj][0] = *(const bf16x8*)&Lb[16384 + (brow + nj * 16) * 64 + cofs0];
      bf[nj][1] = *(const bf16x8*)&Lb[16384 + (brow + nj * 16) * 64 + cofs1];
    }
#pragma unroll
    for (int mi = 0; mi < 4; ++mi) {
      af[mi][0] = *(const bf16x8*)&Lb[(arow + mi * 16) * 64 + cofs0];
      af[mi][1] = *(const bf16x8*)&Lb[(arow + mi * 16) * 64 + cofs1];
    }
    if (t + 2 < nt) STAGE_A((t + 2) % 3, t + 2);
    BARRIER();
    LGKM0(); SCHED0();
    __builtin_amdgcn_s_setprio(1);
#pragma unroll
    for (int ks = 0; ks < 2; ++ks)
#pragma unroll
      for (int mi = 0; mi < 4; ++mi)
#pragma unroll
        for (int nj = 0; nj < 2; ++nj)
          acc[mi][nj] = __builtin_amdgcn_mfma_f32_16x16x32_bf16(af[mi][ks], bf[nj][ks],
                                                                acc[mi][nj], 0, 0, 0);
    __builtin_amdgcn_s_setprio(0);
    SCHED0();
    BARRIER();
    // ======== phase 1: read A mi4-7(8); stage B[t+2]+vmcnt(6); MFMA mi4-7 ========
#pragma unroll
    for (int mi = 0; mi < 4; ++mi) {
      af[mi][0] = *(const bf16x8*)&Lb[(arow + (mi + 4) * 16) * 64 + cofs0];
      af[mi][1] = *(const bf16x8*)&Lb[(arow + (mi + 4) * 16) * 64 + cofs1];
    }
    if (t + 2 < nt) {
      STAGE_B((t + 2) % 3, t + 2);
      VMCNT(6);   // retires tile t+1's 6 loads; t+2's 6 stay in flight
    } else {
      VMCNT(0);   // tail drain (last 2 tiles only)
    }
    BARRIER();
    LGKM0(); SCHED0();
    __builtin_amdgcn_s_setprio(1);
#pragma unroll
    for (int ks = 0; ks < 2; ++ks)
#pragma unroll
      for (int mi = 0; mi < 4; ++mi)
#pragma unroll
        for (int nj = 0; nj < 2; ++nj)
          acc[mi + 4][nj] = __builtin_amdgcn_mfma_f32_16x16x32_bf16(af[mi][ks], bf[nj][ks],
                                                                    acc[mi + 4][nj], 0, 0, 0);
    __builtin_amdgcn_s_setprio(0);
    SCHED0();
    BARRIER();
  }

  // ---- epilogue ----
  if (MODE == 0) {
#pragma unroll
    for (int nj = 0; nj < 2; ++nj) {
      const int c = bn * 128 + wn * 32 + nj * 16 + lm;
      const float bv = bias[c];
      const int which = c >> 10, cc = c & 1023, hh = cc >> 6, d = cc & 63;
#pragma unroll
      for (int mi = 0; mi < 8; ++mi)
#pragma unroll
        for (int i = 0; i < 4; ++i) {
          const int r = bm * 256 + wm * 128 + mi * 16 + lq * 4 + i;
          const int b = r >> 10, s_ = r & 1023;
          float fv = acc[mi][nj][i] + bv;
          if (which == 0) fv *= 0.125f;  // fold 1/sqrt(D) into Q
          const __bf16 v = (__bf16)fv;
          const long hb = (long)(b * 16 + hh);
          if (which == 0)      qo[(hb * 1024 + s_) * 64 + d] = v;
          else if (which == 1) ko[(hb * 1024 + s_) * 64 + d] = v;
          else                 vo[(hb * 64 + d) * 1024 + s_] = v;
        }
    }
  } else {
#pragma unroll
    for (int nj = 0; nj < 2; ++nj) {
      const int c = bn * 128 + wn * 32 + nj * 16 + lm;
      const float bv = bias[c];
#pragma unroll
      for (int mi = 0; mi < 8; ++mi)
#pragma unroll
        for (int i = 0; i < 4; ++i) {
          const int r = bm * 256 + wm * 128 + mi * 16 + lq * 4 + i;
          fo[(long)r * N + c] = acc[mi][nj][i] + bv;
        }
    }
  }
#undef STAGE_A
#undef STAGE_B
}

// ---------------- causal flash attention, fused tile-pair, no LDS ----------------
// softmax + P-pack + PV for one q-tile given its ST accumulator.
__device__ __forceinline__ void sm_pv(f32x16& st, float& m, float& s,
                                      f32x16& o0, f32x16& o1,
                                      const bf16x8 vf[2][2],
                                      int qbw, int k0, bool diag, int lm, int hi) {
  if (diag) {
    const int q = qbw + lm;
#pragma unroll
    for (int r = 0; r < 16; ++r) {
      const int key = k0 + (r & 3) + 8 * (r >> 2) + 4 * hi;
      if (key > q) st[r] = -__builtin_inff();
    }
  }
  float tm = st[0];
#pragma unroll
  for (int r = 1; r < 16; ++r) tm = fmaxf(tm, st[r]);
  tm = fmaxf(tm, __shfl_xor(tm, 32));
  if (!__all(tm <= m + 8.f)) {   // defer-max
    const float mn = fmaxf(m, tm);
    const float fac = __expf(m - mn);
    m = mn;
    s *= fac;
#pragma unroll
    for (int r = 0; r < 16; ++r) {
      const int qr = (r & 3) + 8 * (r >> 2) + 4 * hi;
      const float fr = __int_as_float(
          __builtin_amdgcn_ds_bpermute(qr * 4, __float_as_int(fac)));
      o0[r] *= fr; o1[r] *= fr;
    }
  }
  float p[16], ts = 0.f;
#pragma unroll
  for (int r = 0; r < 16; ++r) { p[r] = __expf(st[r] - m); ts += p[r]; }
  ts += __shfl_xor(ts, 32);
  s += ts;
  unsigned int w8[8];
#pragma unroll
  for (int t = 0; t < 8; ++t) {
    union { __bf16 hh[2]; unsigned int u; } pk;
    pk.hh[0] = (__bf16)p[2 * t]; pk.hh[1] = (__bf16)p[2 * t + 1];
    w8[t] = pk.u;
  }
  const unsigned int e0 = __shfl_xor(hi ? w8[0] : w8[2], 32);
  const unsigned int e1 = __shfl_xor(hi ? w8[1] : w8[3], 32);
  const unsigned int e2 = __shfl_xor(hi ? w8[4] : w8[6], 32);
  const unsigned int e3 = __shfl_xor(hi ? w8[5] : w8[7], 32);
  union { unsigned int wd[4]; bf16x8 v; } pa0, pa1;
  if (hi) {
    pa0.wd[0] = e0;    pa0.wd[1] = e1;    pa0.wd[2] = w8[2]; pa0.wd[3] = w8[3];
    pa1.wd[0] = e2;    pa1.wd[1] = e3;    pa1.wd[2] = w8[6]; pa1.wd[3] = w8[7];
  } else {
    pa0.wd[0] = w8[0]; pa0.wd[1] = w8[1]; pa0.wd[2] = e0;    pa0.wd[3] = e1;
    pa1.wd[0] = w8[4]; pa1.wd[1] = w8[5]; pa1.wd[2] = e2;    pa1.wd[3] = e3;
  }
#pragma unroll
  for (int t = 0; t < 2; ++t) {
    const bf16x8 pa = t ? pa1.v : pa0.v;
    o0 = __builtin_amdgcn_mfma_f32_32x32x16_bf16(pa, vf[t][0], o0, 0, 0, 0);
    o1 = __builtin_amdgcn_mfma_f32_32x32x16_bf16(pa, vf[t][1], o1, 0, 0, 0);
  }
}

__device__ __forceinline__ void attn_write(const f32x16& o0, const f32x16& o1, float s,
                                           __bf16* __restrict__ ob,
                                           int b, int h, int qbw, int lm, int hi) {
  const float invs = 1.f / s;
#pragma unroll
  for (int r = 0; r < 16; ++r) {
    const int qr = (r & 3) + 8 * (r >> 2) + 4 * hi;
    const float inv = __int_as_float(
        __builtin_amdgcn_ds_bpermute(qr * 4, __float_as_int(invs)));
    const long row = (long)(b * 1024 + qbw + qr) * 1024 + h * 64;
    ob[row + lm]      = (__bf16)(o0[r] * inv);
    ob[row + 32 + lm] = (__bf16)(o1[r] * inv);
  }
}

// grid (4, B*H), 4 waves. Wave wi fuses q-tiles A=wi (short) and B=31-wi (long):
// shared K/V loads, two independent softmax chains per kt iteration.
__global__ void k_attn(const __bf16* __restrict__ qb_, const __bf16* __restrict__ kb,
                       const __bf16* __restrict__ vtb, __bf16* __restrict__ ob) {
  const int l = threadIdx.x & 63, w = threadIdx.x >> 6;
  const int lm = l & 31, hi = l >> 5;
  const int bh = blockIdx.y, b = bh >> 4, h = bh & 15;
  const int wi = blockIdx.x * 4 + w;  // 0..15
  const __bf16* Q  = qb_ + (long)bh * 65536;
  const __bf16* Kh = kb  + (long)bh * 65536;
  const __bf16* Vt = vtb + (long)bh * 65536;

  const int qbA = wi * 32,        ntA = wi + 1;
  const int qbB = (31 - wi) * 32, ntB = 32 - wi;

  bf16x8 qfA[4], qfB[4];
#pragma unroll
  for (int ds = 0; ds < 4; ++ds) {
    qfA[ds] = *(const bf16x8*)(Q + (long)(qbA + lm) * 64 + ds * 16 + hi * 8);
    qfB[ds] = *(const bf16x8*)(Q + (long)(qbB + lm) * 64 + ds * 16 + hi * 8);
  }

  f32x16 oA0 = {}, oA1 = {}, oB0 = {}, oB1 = {};
  float mA = -__builtin_inff(), sA = 0.f;
  float mB = -__builtin_inff(), sB = 0.f;

  for (int kt = 0; kt < ntB; ++kt) {
    const int k0 = kt * 32;
    const bool actA = (kt < ntA);
    // shared K fragments
    bf16x8 kf[4];
#pragma unroll
    for (int ds = 0; ds < 4; ++ds)
      kf[ds] = *(const bf16x8*)(Kh + (long)(k0 + lm) * 64 + ds * 16 + hi * 8);
    f32x16 stA = {}, stB = {};
#pragma unroll
    for (int ds = 0; ds < 4; ++ds)
      stB = __builtin_amdgcn_mfma_f32_32x32x16_bf16(kf[ds], qfB[ds], stB, 0, 0, 0);
    if (actA) {
#pragma unroll
      for (int ds = 0; ds < 4; ++ds)
        stA = __builtin_amdgcn_mfma_f32_32x32x16_bf16(kf[ds], qfA[ds], stA, 0, 0, 0);
    }
    // shared V fragments
    bf16x8 vf[2][2];
#pragma unroll
    for (int t = 0; t < 2; ++t) {
      vf[t][0] = *(const bf16x8*)(Vt + (long)lm * 1024 + k0 + t * 16 + hi * 8);
      vf[t][1] = *(const bf16x8*)(Vt + (long)(32 + lm) * 1024 + k0 + t * 16 + hi * 8);
    }
    if (actA) sm_pv(stA, mA, sA, oA0, oA1, vf, qbA, k0, kt == ntA - 1, lm, hi);
    sm_pv(stB, mB, sB, oB0, oB1, vf, qbB, k0, kt == ntB - 1, lm, hi);
  }
  attn_write(oA0, oA1, sA, ob, b, h, qbA, lm, hi);
  attn_write(oB0, oB1, sB, ob, b, h, qbB, lm, hi);
}

extern "C" void kernel_launch(void* const* d_in, const int* in_sizes, int n_in,
                              void* d_out, int out_size, void* d_ws, size_t ws_size,
                              hipStream_t stream) {
  const float* x      = (const float*)d_in[0];
  const float* w_attn = (const float*)d_in[1];
  const float* b_attn = (const float*)d_in[2];
  const float* w_proj = (const float*)d_in[3];
  const float* b_proj = (const float*)d_in[4];
  float* out = (float*)d_out;

  char* ws = (char*)d_ws;
  const size_t SZ_XBF = (size_t)8192 * 1024 * 2;   // 16.8 MB
  __bf16* x_bf = (__bf16*)ws;  ws += SZ_XBF;
  __bf16* wat  = (__bf16*)ws;  ws += (size_t)3072 * 1024 * 2;
  __bf16* wpt  = (__bf16*)ws;  ws += (size_t)1024 * 1024 * 2;
  __bf16* qb   = (__bf16*)ws;  ws += SZ_XBF;       // [B,H,S,D], pre-scaled 1/8
  __bf16* kb   = (__bf16*)ws;  ws += SZ_XBF;       // [B,H,S,D]
  __bf16* vtb  = (__bf16*)ws;  ws += SZ_XBF;       // [B,H,D,S]
  __bf16* obf  = (__bf16*)ws;  ws += SZ_XBF;       // [B,S,NX]

  k_cast<<<8192, 256, 0, stream>>>(x, x_bf, 2097152);
  k_transpose_cast<<<dim3(96, 32), 256, 0, stream>>>(w_attn, wat, 1024, 3072);
  k_transpose_cast<<<dim3(32, 32), 256, 0, stream>>>(w_proj, wpt, 1024, 1024);
  // QKV: M=8192, N=3072 -> 32x24 = 768 blocks (3 exact CU rounds)
  k_gemm_p<0><<<768, 512, 0, stream>>>(x_bf, wat, b_attn, 8192, 3072, 1024, 24,
                                       qb, kb, vtb, nullptr);
  k_attn<<<dim3(4, 128), 256, 0, stream>>>(qb, kb, vtb, obf);
  // proj: M=8192, N=1024 -> 32x8 = 256 blocks (1 exact CU round)
  k_gemm_p<1><<<256, 512, 0, stream>>>(obf, wpt, b_proj, 8192, 1024, 1024, 8,
                                       nullptr, nullptr, nullptr, out);
}

// Round 6
// 287.524 us; speedup vs baseline: 1.1539x; 1.1539x over previous
//
#include <hip/hip_runtime.h>
#include <hip/hip_bf16.h>
#include <stdint.h>

// B=8, S=1024, NX=1024, H=16, D=64
typedef __bf16 bf16x8 __attribute__((ext_vector_type(8)));
typedef float  f32x4  __attribute__((ext_vector_type(4)));
typedef float  f32x16 __attribute__((ext_vector_type(16)));

#define BARRIER() asm volatile("s_barrier" ::: "memory")
#define VMCNT(n)  asm volatile("s_waitcnt vmcnt(" #n ")" ::: "memory")
#define LGKM0()   asm volatile("s_waitcnt lgkmcnt(0)" ::: "memory")
#define SCHED0()  __builtin_amdgcn_sched_barrier(0)

__device__ __forceinline__ void gload_lds16(const void* g, void* l) {
  __builtin_amdgcn_global_load_lds(
      (const __attribute__((address_space(1))) unsigned int*)g,
      (__attribute__((address_space(3))) unsigned int*)l, 16, 0, 0);
}

// ---------------- cast fp32 -> bf16, 4 elems/thread ----------------
__global__ void k_cast(const float* __restrict__ in, __bf16* __restrict__ out, int n4) {
  int i = blockIdx.x * blockDim.x + threadIdx.x;
  if (i >= n4) return;
  float4 v = reinterpret_cast<const float4*>(in)[i];
  union { __bf16 h[4]; uint64_t u; } c;
  c.h[0] = (__bf16)v.x; c.h[1] = (__bf16)v.y; c.h[2] = (__bf16)v.z; c.h[3] = (__bf16)v.w;
  *reinterpret_cast<uint64_t*>(out + 4l * i) = c.u;
}

// ------------- transpose fp32 [R][C] -> bf16 [C][R] ----------------
__global__ void k_transpose_cast(const float* __restrict__ in, __bf16* __restrict__ out,
                                 int R, int C) {
  __shared__ float t[32][33];
  const int tx = threadIdx.x & 31, ty = threadIdx.x >> 5;  // 32 x 8
  const int c0 = blockIdx.x * 32, r0 = blockIdx.y * 32;
#pragma unroll
  for (int rr = 0; rr < 4; ++rr)
    t[ty * 4 + rr][tx] = in[(long)(r0 + ty * 4 + rr) * C + c0 + tx];
  __syncthreads();
#pragma unroll
  for (int rr = 0; rr < 4; ++rr)
    out[(long)(c0 + ty * 4 + rr) * R + r0 + tx] = (__bf16)t[tx][ty * 4 + rr];
}

// ============ pipelined GEMM: C = A[M,K] * Bt[N,K]^T + bias ============
// Tile 256x128, BK=64, 8 waves (2m x 4n), per-wave C = 128x32 (acc[8][2]).
// LDS: 3 rotating buffers x {A 256x64 (32K), B 128x64 (16K)} = 144 KB.
// Prefetch depth = 2 K-tiles; stage A[t+2] in ph0, B[t+2]+vmcnt(6) in ph1.
// Steady state 6-12 loads in flight; vmcnt(0) only on the last 2 tiles.
// Swizzle (T2): byte-col ^= ((row&7)<<4) on gload source AND ds_read.
// MODE 0: scatter -> q[B,H,S,D] (pre-scaled 1/8), k[B,H,S,D], v^T[B,H,D,S]
// MODE 1: fp32 -> fo[M,N]
template <int MODE>
__launch_bounds__(512, 2)
__global__ void k_gemm_p(const __bf16* __restrict__ A, const __bf16* __restrict__ Bt,
                         const float* __restrict__ bias, int M, int N, int K, int NB,
                         __bf16* __restrict__ qo, __bf16* __restrict__ ko,
                         __bf16* __restrict__ vo, float* __restrict__ fo) {
  __shared__ __bf16 lds[3][24576];  // [buf][A: 0..16384 | B: 16384..24576]
  const int tid = threadIdx.x;
  const int l = tid & 63;
  const int w = tid >> 6;
  const int lm = l & 15, lq = l >> 4;
  const int wm = w >> 2, wn = w & 3;
  const int nwg = gridDim.x;
  const int wg = (blockIdx.x & 7) * (nwg >> 3) + (blockIdx.x >> 3);  // XCD swizzle (nwg%8==0)
  const int bm = wg / NB, bn = wg % NB;
  const int nt = K >> 6;

  // ---- staging addresses: thread covers row (tid>>3)+li*64, 16B at swizzled col ----
  const int rA = tid >> 3;
  const int scol = (((tid & 7) * 16) ^ ((rA & 7) << 4)) >> 1;  // element col (swizzled)
  long a_off[4], b_off[2];
#pragma unroll
  for (int li = 0; li < 4; ++li) a_off[li] = (long)(bm * 256 + li * 64 + rA) * K + scol;
#pragma unroll
  for (int li = 0; li < 2; ++li) b_off[li] = (long)(bn * 128 + li * 64 + rA) * K + scol;

#define STAGE_A(buf, t) { \
    gload_lds16(A + a_off[0] + (long)(t) * 64, &lds[buf][tid * 8]); \
    gload_lds16(A + a_off[1] + (long)(t) * 64, &lds[buf][4096 + tid * 8]); \
    gload_lds16(A + a_off[2] + (long)(t) * 64, &lds[buf][8192 + tid * 8]); \
    gload_lds16(A + a_off[3] + (long)(t) * 64, &lds[buf][12288 + tid * 8]); }
#define STAGE_B(buf, t) { \
    gload_lds16(Bt + b_off[0] + (long)(t) * 64, &lds[buf][16384 + tid * 8]); \
    gload_lds16(Bt + b_off[1] + (long)(t) * 64, &lds[buf][20480 + tid * 8]); }

  // ---- fragment read offsets ----
  const int aswz = (lm & 7) << 4;
  const int cofs0 = ((0 * 64 + lq * 16) ^ aswz) >> 1;   // ks=0 element col
  const int cofs1 = ((1 * 64 + lq * 16) ^ aswz) >> 1;   // ks=1
  const int arow = wm * 128 + lm;                        // + mi*16
  const int brow = wn * 32 + lm;                         // + nj*16

  f32x4 acc[8][2] = {};

  // ---- prologue: stage tiles 0,1 (12 loads); retire tile 0's 6 ----
  STAGE_A(0, 0); STAGE_B(0, 0);
  STAGE_A(1, 1); STAGE_B(1, 1);
  VMCNT(6); BARRIER();

  for (int t = 0; t < nt; ++t) {
    const int cb = t % 3;
    const __bf16* Lb = lds[cb];
    // ======== phase 0: read B(4) + A mi0-3(8); stage A[t+2]; MFMA mi0-3 ========
    bf16x8 bf[2][2], af[4][2];
#pragma unroll
    for (int nj = 0; nj < 2; ++nj) {
      bf[nj][0] = *(const bf16x8*)&Lb[16384 + (brow + nj * 16) * 64 + cofs0];
      bf[nj][1] = *(const bf16x8*)&Lb[16384 + (brow + nj * 16) * 64 + cofs1];
    }
#pragma unroll
    for (int mi = 0; mi < 4; ++mi) {
      af[mi][0] = *(const bf16x8*)&Lb[(arow + mi * 16) * 64 + cofs0];
      af[mi][1] = *(const bf16x8*)&Lb[(arow + mi * 16) * 64 + cofs1];
    }
    if (t + 2 < nt) STAGE_A((t + 2) % 3, t + 2);
    BARRIER();
    LGKM0(); SCHED0();
    __builtin_amdgcn_s_setprio(1);
#pragma unroll
    for (int ks = 0; ks < 2; ++ks)
#pragma unroll
      for (int mi = 0; mi < 4; ++mi)
#pragma unroll
        for (int nj = 0; nj < 2; ++nj)
          acc[mi][nj] = __builtin_amdgcn_mfma_f32_16x16x32_bf16(af[mi][ks], bf[nj][ks],
                                                                acc[mi][nj], 0, 0, 0);
    __builtin_amdgcn_s_setprio(0);
    SCHED0();
    BARRIER();
    // ======== phase 1: read A mi4-7(8); stage B[t+2]+vmcnt(6); MFMA mi4-7 ========
#pragma unroll
    for (int mi = 0; mi < 4; ++mi) {
      af[mi][0] = *(const bf16x8*)&Lb[(arow + (mi + 4) * 16) * 64 + cofs0];
      af[mi][1] = *(const bf16x8*)&Lb[(arow + (mi + 4) * 16) * 64 + cofs1];
    }
    if (t + 2 < nt) {
      STAGE_B((t + 2) % 3, t + 2);
      VMCNT(6);   // retires tile t+1's 6 loads; t+2's 6 stay in flight
    } else {
      VMCNT(0);   // tail drain (last 2 tiles only)
    }
    BARRIER();
    LGKM0(); SCHED0();
    __builtin_amdgcn_s_setprio(1);
#pragma unroll
    for (int ks = 0; ks < 2; ++ks)
#pragma unroll
      for (int mi = 0; mi < 4; ++mi)
#pragma unroll
        for (int nj = 0; nj < 2; ++nj)
          acc[mi + 4][nj] = __builtin_amdgcn_mfma_f32_16x16x32_bf16(af[mi][ks], bf[nj][ks],
                                                                    acc[mi + 4][nj], 0, 0, 0);
    __builtin_amdgcn_s_setprio(0);
    SCHED0();
    BARRIER();
  }

  // ---- epilogue ----
  if (MODE == 0) {
#pragma unroll
    for (int nj = 0; nj < 2; ++nj) {
      const int c = bn * 128 + wn * 32 + nj * 16 + lm;
      const float bv = bias[c];
      const int which = c >> 10, cc = c & 1023, hh = cc >> 6, d = cc & 63;
#pragma unroll
      for (int mi = 0; mi < 8; ++mi)
#pragma unroll
        for (int i = 0; i < 4; ++i) {
          const int r = bm * 256 + wm * 128 + mi * 16 + lq * 4 + i;
          const int b = r >> 10, s_ = r & 1023;
          float fv = acc[mi][nj][i] + bv;
          if (which == 0) fv *= 0.125f;  // fold 1/sqrt(D) into Q
          const __bf16 v = (__bf16)fv;
          const long hb = (long)(b * 16 + hh);
          if (which == 0)      qo[(hb * 1024 + s_) * 64 + d] = v;
          else if (which == 1) ko[(hb * 1024 + s_) * 64 + d] = v;
          else                 vo[(hb * 64 + d) * 1024 + s_] = v;
        }
    }
  } else {
#pragma unroll
    for (int nj = 0; nj < 2; ++nj) {
      const int c = bn * 128 + wn * 32 + nj * 16 + lm;
      const float bv = bias[c];
#pragma unroll
      for (int mi = 0; mi < 8; ++mi)
#pragma unroll
        for (int i = 0; i < 4; ++i) {
          const int r = bm * 256 + wm * 128 + mi * 16 + lq * 4 + i;
          fo[(long)r * N + c] = acc[mi][nj][i] + bv;
        }
    }
  }
#undef STAGE_A
#undef STAGE_B
}

// ---------------- causal flash attention, 32x32 swapped-QK^T, no LDS ----------------
// One q-tile per wave-state at a time (no fusion: fusing spilled to scratch, R3).
__device__ __forceinline__ void attn_qtile(const __bf16* __restrict__ Q,
                                           const __bf16* __restrict__ Kh,
                                           const __bf16* __restrict__ Vt,
                                           __bf16* __restrict__ ob,
                                           int b, int h, int qbw, int l) {
  const int lm = l & 31, hi = l >> 5;

  bf16x8 qf[4];
#pragma unroll
  for (int ds = 0; ds < 4; ++ds)
    qf[ds] = *(const bf16x8*)(Q + (long)(qbw + lm) * 64 + ds * 16 + hi * 8);

  f32x16 oacc0 = {}, oacc1 = {};
  float m = -__builtin_inff(), s = 0.f;

  const int ntiles = (qbw >> 5) + 1;
  for (int kt = 0; kt < ntiles; ++kt) {
    const int k0 = kt * 32;
    f32x16 st = {};
#pragma unroll
    for (int ds = 0; ds < 4; ++ds) {
      bf16x8 kf = *(const bf16x8*)(Kh + (long)(k0 + lm) * 64 + ds * 16 + hi * 8);
      st = __builtin_amdgcn_mfma_f32_32x32x16_bf16(kf, qf[ds], st, 0, 0, 0);
    }
    if (kt == ntiles - 1) {
      const int q = qbw + lm;
#pragma unroll
      for (int r = 0; r < 16; ++r) {
        const int key = k0 + (r & 3) + 8 * (r >> 2) + 4 * hi;
        if (key > q) st[r] = -__builtin_inff();
      }
    }
    float tm = st[0];
#pragma unroll
    for (int r = 1; r < 16; ++r) tm = fmaxf(tm, st[r]);
    tm = fmaxf(tm, __shfl_xor(tm, 32));
    if (!__all(tm <= m + 8.f)) {   // defer-max
      const float mn = fmaxf(m, tm);
      const float fac = __expf(m - mn);
      m = mn;
      s *= fac;
#pragma unroll
      for (int r = 0; r < 16; ++r) {
        const int qr = (r & 3) + 8 * (r >> 2) + 4 * hi;
        const float fr = __int_as_float(
            __builtin_amdgcn_ds_bpermute(qr * 4, __float_as_int(fac)));
        oacc0[r] *= fr; oacc1[r] *= fr;
      }
    }
    float p[16], ts = 0.f;
#pragma unroll
    for (int r = 0; r < 16; ++r) { p[r] = __expf(st[r] - m); ts += p[r]; }
    ts += __shfl_xor(ts, 32);
    s += ts;
    unsigned int w8[8];
#pragma unroll
    for (int t = 0; t < 8; ++t) {
      union { __bf16 hh[2]; unsigned int u; } pk;
      pk.hh[0] = (__bf16)p[2 * t]; pk.hh[1] = (__bf16)p[2 * t + 1];
      w8[t] = pk.u;
    }
    const unsigned int e0 = __shfl_xor(hi ? w8[0] : w8[2], 32);
    const unsigned int e1 = __shfl_xor(hi ? w8[1] : w8[3], 32);
    const unsigned int e2 = __shfl_xor(hi ? w8[4] : w8[6], 32);
    const unsigned int e3 = __shfl_xor(hi ? w8[5] : w8[7], 32);
    union { unsigned int wd[4]; bf16x8 v; } pa0, pa1;
    if (hi) {
      pa0.wd[0] = e0;    pa0.wd[1] = e1;    pa0.wd[2] = w8[2]; pa0.wd[3] = w8[3];
      pa1.wd[0] = e2;    pa1.wd[1] = e3;    pa1.wd[2] = w8[6]; pa1.wd[3] = w8[7];
    } else {
      pa0.wd[0] = w8[0]; pa0.wd[1] = w8[1]; pa0.wd[2] = e0;    pa0.wd[3] = e1;
      pa1.wd[0] = w8[4]; pa1.wd[1] = w8[5]; pa1.wd[2] = e2;    pa1.wd[3] = e3;
    }
#pragma unroll
    for (int t = 0; t < 2; ++t) {
      const bf16x8 pa = t ? pa1.v : pa0.v;
      bf16x8 vf0 = *(const bf16x8*)(Vt + (long)lm * 1024 + k0 + t * 16 + hi * 8);
      bf16x8 vf1 = *(const bf16x8*)(Vt + (long)(32 + lm) * 1024 + k0 + t * 16 + hi * 8);
      oacc0 = __builtin_amdgcn_mfma_f32_32x32x16_bf16(pa, vf0, oacc0, 0, 0, 0);
      oacc1 = __builtin_amdgcn_mfma_f32_32x32x16_bf16(pa, vf1, oacc1, 0, 0, 0);
    }
  }
  const float invs = 1.f / s;
#pragma unroll
  for (int r = 0; r < 16; ++r) {
    const int qr = (r & 3) + 8 * (r >> 2) + 4 * hi;
    const float inv = __int_as_float(
        __builtin_amdgcn_ds_bpermute(qr * 4, __float_as_int(invs)));
    const long row = (long)(b * 1024 + qbw + qr) * 1024 + h * 64;
    ob[row + lm]      = (__bf16)(oacc0[r] * inv);
    ob[row + 32 + lm] = (__bf16)(oacc1[r] * inv);
  }
}

// 512 blocks, XCD-affinity mapping: the 4 blocks of one (b,h) get ids congruent
// mod 8 -> same XCD -> K/V panel (256 KB) stays in that XCD's L2.
__global__ void k_attn(const __bf16* __restrict__ qb_, const __bf16* __restrict__ kb,
                       const __bf16* __restrict__ vtb, __bf16* __restrict__ ob) {
  const int l = threadIdx.x & 63, w = threadIdx.x >> 6;
  const int bid = blockIdx.x;
  const int xcd = bid & 7, slot = bid >> 3;      // slot 0..63
  const int bh = xcd + 8 * (slot >> 2);          // 16 bh-groups per XCD
  const int j = slot & 3;
  const int wi = j * 4 + w;                      // 0..15
  const int b = bh >> 4, h = bh & 15;
  const __bf16* Q  = qb_ + (long)bh * 65536;
  const __bf16* Kh = kb  + (long)bh * 65536;
  const __bf16* Vt = vtb + (long)bh * 65536;
  attn_qtile(Q, Kh, Vt, ob, b, h, wi * 32, l);
  attn_qtile(Q, Kh, Vt, ob, b, h, (31 - wi) * 32, l);
}

extern "C" void kernel_launch(void* const* d_in, const int* in_sizes, int n_in,
                              void* d_out, int out_size, void* d_ws, size_t ws_size,
                              hipStream_t stream) {
  const float* x      = (const float*)d_in[0];
  const float* w_attn = (const float*)d_in[1];
  const float* b_attn = (const float*)d_in[2];
  const float* w_proj = (const float*)d_in[3];
  const float* b_proj = (const float*)d_in[4];
  float* out = (float*)d_out;

  char* ws = (char*)d_ws;
  const size_t SZ_XBF = (size_t)8192 * 1024 * 2;   // 16.8 MB
  __bf16* x_bf = (__bf16*)ws;  ws += SZ_XBF;
  __bf16* wat  = (__bf16*)ws;  ws += (size_t)3072 * 1024 * 2;
  __bf16* wpt  = (__bf16*)ws;  ws += (size_t)1024 * 1024 * 2;
  __bf16* qb   = (__bf16*)ws;  ws += SZ_XBF;       // [B,H,S,D], pre-scaled 1/8
  __bf16* kb   = (__bf16*)ws;  ws += SZ_XBF;       // [B,H,S,D]
  __bf16* vtb  = (__bf16*)ws;  ws += SZ_XBF;       // [B,H,D,S]
  __bf16* obf  = (__bf16*)ws;  ws += SZ_XBF;       // [B,S,NX]

  k_cast<<<8192, 256, 0, stream>>>(x, x_bf, 2097152);
  k_transpose_cast<<<dim3(96, 32), 256, 0, stream>>>(w_attn, wat, 1024, 3072);
  k_transpose_cast<<<dim3(32, 32), 256, 0, stream>>>(w_proj, wpt, 1024, 1024);
  // QKV: M=8192, N=3072 -> 32x24 = 768 blocks (3 exact CU rounds)
  k_gemm_p<0><<<768, 512, 0, stream>>>(x_bf, wat, b_attn, 8192, 3072, 1024, 24,
                                       qb, kb, vtb, nullptr);
  k_attn<<<512, 256, 0, stream>>>(qb, kb, vtb, obf);
  // proj: M=8192, N=1024 -> 32x8 = 256 blocks (1 exact CU round)
  k_gemm_p<1><<<256, 512, 0, stream>>>(obf, wpt, b_proj, 8192, 1024, 1024, 8,
                                       nullptr, nullptr, nullptr, out);
}